// Round 1
// 57.969 us; speedup vs baseline: 1.0020x; 1.0020x over previous
//
#include <hip/hip_runtime.h>
#include <math.h>

#define N_BINS   64
#define EPS_W    0.001f
#define LUT_SIZE 256
#define BLOCK    64     // one wave per block: no __syncthreads needed anywhere
#define VEC      4      // float4 per thread

__device__ inline float wave_sum(float v) {
    #pragma unroll
    for (int off = 32; off >= 1; off >>= 1) v += __shfl_xor(v, off, 64);
    return v;
}
__device__ inline float wave_max(float v) {
    #pragma unroll
    for (int off = 32; off >= 1; off >>= 1) v = fmaxf(v, __shfl_xor(v, off, 64));
    return v;
}
__device__ inline float wave_scan_incl(float v, int lane) {
    #pragma unroll
    for (int off = 1; off < 64; off <<= 1) {
        float o = __shfl_up(v, off, 64);
        if (lane >= off) v += o;
    }
    return v;
}

// Exact reference semantics from any starting hint:
// down-walk to enforce e_t[idx] <= tp, then up-walk to maximality.
// The LUT is only a hint; correctness never depends on it.
__device__ inline float lookup_one(const float4* __restrict__ bin,
                                   const int*    __restrict__ lut,
                                   float tp)
{
    int k = (int)(tp * (float)LUT_SIZE);
    k = min(max(k, 0), LUT_SIZE - 1);
    int idx = lut[k];
    idx = min(max(idx, 0), N_BINS - 1);          // garbage-proof clamp
    float4 b = bin[idx];
    while (idx > 0 && b.x > tp)            b = bin[--idx];
    while (idx < N_BINS - 1 && b.w <= tp)  b = bin[++idx];
    return fmaf(b.z, tp - b.x, b.y);
}

__global__ __launch_bounds__(BLOCK) void losscdf_kernel(
    const float* __restrict__ t,
    const float* __restrict__ l_t,
    const float* __restrict__ l_u,
    float* __restrict__ out,
    int n)
{
    __shared__ float4 s_bin[N_BINS];    // {et0, eu0, slope, et1} per bin
    __shared__ int    s_lut[LUT_SIZE];  // floor(t*256) -> starting idx hint

    const int lane = threadIdx.x;       // BLOCK == 64: exactly one wave

    // ---- issue the element load FIRST: its HBM latency hides under the
    //      table build below (no barrier in this kernel ever drains vmcnt
    //      before we actually consume tp4) ----
    const int  gi   = blockIdx.x * BLOCK + lane;   // float4 index
    const long base = (long)gi * VEC;
    const bool full = (base + VEC <= (long)n);
    float4 tp4 = make_float4(0.f, 0.f, 0.f, 0.f);
    if (full) tp4 = reinterpret_cast<const float4*>(t)[gi];

    // params (256 B, L2-resident after the first blocks) — also issued early
    float lt = l_t[lane];
    float lu = l_u[lane];

    // ---- per-wave table build (identical numerics to the passing kernel) ----
    float m   = wave_max(lt);
    float ex  = expf(lt - m);
    float se  = wave_sum(ex);
    float wt  = ex / se + EPS_W;        // w_t = softmax(l_t) + eps
    float swt = wave_sum(wt);
    wt = wt / swt;                      // renormalized

    float eu  = expf(lu) + EPS_W;       // w_u = exp(l_u) + eps
    float seu = wave_sum(eu);
    float wu  = eu / seu;               // normalized

    float ct = wave_scan_incl(wt, lane);  // e_t[lane+1]
    float cu = wave_scan_incl(wu, lane);  // e_u[lane+1]

    float et1 = ct;
    float et0 = ct - wt;
    float eu0 = cu - wu;
    if (lane == 0) { et0 = 0.0f; eu0 = 0.0f; }

    float4 b;
    b.x = et0;
    b.y = eu0;
    b.z = (cu - eu0) / (et1 - et0);
    b.w = et1;
    s_bin[lane] = b;

    // LUT by stamping: lane (= bin) writes its index into every slot whose
    // start lies inside [et0, et1). Slots partition exactly across lanes
    // (k >= ceil(et0*256) && k < ceil(et1*256)); ~4 writes/lane, no
    // dependent-read chain. Lane 63 force-covers the tail against fp drift.
    int k0 = (int)ceilf(et0 * (float)LUT_SIZE);
    int k1 = (int)ceilf(et1 * (float)LUT_SIZE);
    k0 = max(k0, 0);
    k1 = (lane == N_BINS - 1) ? LUT_SIZE : min(k1, LUT_SIZE);
    for (int k = k0; k < k1; ++k) s_lut[k] = lane;

    // ---- lookups: 4 elements, one float4 store ----
    if (full) {
        float4 r;
        r.x = lookup_one(s_bin, s_lut, tp4.x);
        r.y = lookup_one(s_bin, s_lut, tp4.y);
        r.z = lookup_one(s_bin, s_lut, tp4.z);
        r.w = lookup_one(s_bin, s_lut, tp4.w);
        reinterpret_cast<float4*>(out)[gi] = r;
    } else if (base < (long)n) {
        // tail (n not a multiple of 4) — scalar path
        for (long e = base; e < (long)n; ++e)
            out[e] = lookup_one(s_bin, s_lut, t[e]);
    }
}

extern "C" void kernel_launch(void* const* d_in, const int* in_sizes, int n_in,
                              void* d_out, int out_size, void* d_ws, size_t ws_size,
                              hipStream_t stream) {
    const float* t   = (const float*)d_in[0];
    const float* l_t = (const float*)d_in[1];
    const float* l_u = (const float*)d_in[2];
    float* out = (float*)d_out;
    int n = in_sizes[0];                           // 32*4096 = 131072
    int grid = (n + BLOCK * VEC - 1) / (BLOCK * VEC);  // 512 blocks
    if (grid < 1) grid = 1;
    losscdf_kernel<<<grid, BLOCK, 0, stream>>>(t, l_t, l_u, out, n);
}